// Round 8
// baseline (331.602 us; speedup 1.0000x reference)
//
#include <hip/hip_runtime.h>

// NCA forward, fully-fused MFMA version.
// Perception folded into GEMM1: h = relu(xn @ W1eff + b1), where xn is the
// 3x3 neighborhood (9 pos x 16 ch = K 144, padded to 160; k=144 is a
// constant-1.0 bias slot). GEMM2 runs swapped (dxT = W2piT . hT) with W2's
// hidden dim pi-permuted at prep time so the B-fragment is exactly the
// relu+packed D1T registers -- no h round-trip through LDS.

#define Hn 512
#define Cn 16

typedef __attribute__((ext_vector_type(8))) __bf16 bf16v8;
typedef __attribute__((ext_vector_type(4))) float f32x4;

#define W1E_SH (128 * 160)          // W1effT [n=128][k=160] bf16
#define W2P_SH (2 * 16 * 64)        // W2pi [slice][out=16][k=64] bf16
#define WS_TOT (W1E_SH + W2P_SH)    // 22528 shorts

__device__ __forceinline__ unsigned short f2bf(float f) {
    return __builtin_bit_cast(unsigned short, (__bf16)f);
}
__device__ __forceinline__ unsigned pk2(float a, float b) {
    return (unsigned)f2bf(a) | ((unsigned)f2bf(b) << 16);
}

// ---- prep: build W1effT (perception folded into W1) and pi-permuted W2T ----
__global__ void nca_prep(const float* __restrict__ W1, const float* __restrict__ b1,
                         const float* __restrict__ W2, unsigned short* __restrict__ ws)
{
    int i = blockIdx.x * 256 + threadIdx.x;
    if (i >= WS_TOT) return;
    float v;
    if (i < W1E_SH) {
        int n = i / 160, k = i - n * 160;
        if (k < 144) {
            int p = k >> 4, c = k & 15;           // p = dy*3+dx, c = channel
            // sobel-x/8 and sobel-y/8 coefficients by position p
            const int sxi = ((0x24924u >> (2 * p)) & 3) - 1;          // dx-1
            const int syi = ((0x2A540u >> (2 * p)) & 3) - 1;          // dy-1
            const float sxv = (float)sxi * (syi == 0 ? 0.25f : 0.125f); // -1,0,1 / -2,0,2 /8
            const float syv = (float)syi * (sxi == 0 ? 0.25f : 0.125f);
            v = sxv * W1[(3 * c + 1) * 128 + n] + syv * W1[(3 * c + 2) * 128 + n];
            if (p == 4) v += W1[(3 * c + 0) * 128 + n];               // identity center
        } else if (k == 144) v = b1[n];            // bias slot (xn k=144 == 1.0)
        else v = 0.f;
    } else {
        int j = i - W1E_SH;
        int s = j >> 10, rem = j & 1023;
        int o = rem >> 6, kl = rem & 63;
        int kc = kl >> 5, g = (kl >> 3) & 3, jj = kl & 7;
        int hid = 64 * s + 16 * (2 * kc + (jj >> 2)) + 4 * g + (jj & 3);  // pi
        v = W2[hid * 16 + o];
    }
    ws[i] = f2bf(v);
}

// tile 16x8 px, 4 waves: 2-way pixel split (rows 0-3 / 4-7) x 2-way hidden
// split (hid 0-63 / 64-127). Partial dx reduced via padded f32 LDS buffer.
__global__ __launch_bounds__(256, 2) void nca_fwd(
    const float* __restrict__ x,
    const unsigned short* __restrict__ ws,
    const float* __restrict__ b2,
    float* __restrict__ out)
{
    __shared__ unsigned short xn[10 * 18 * 24];   // halo [hy][hx][24ch] bf16, 8640 B
    __shared__ float red[8][2][16][20];           // [row][slice][px][out pad20] 20480 B

    const int tid = threadIdx.x;
    const int blk = blockIdx.x;
    const int bImg = blk >> 11;                   // 2048 tiles (64y x 32x) per image
    const int tt = blk & 2047;
    const int Ybase = (tt >> 5) << 3;
    const int Xbase = (tt & 31) << 4;

    // ---- stage halo as bf16 (c16 = 1.0 bias flag, c17..23 = 0) ----
    if (tid < 180) {
        const int hy = tid / 18;
        const int hx = tid - hy * 18;
        const int gy = Ybase + hy - 1;
        const int gx = Xbase + hx - 1;
        const bool ok = ((unsigned)gy < Hn) && ((unsigned)gx < Hn);
        float4 v0 = {0,0,0,0}, v1 = v0, v2 = v0, v3 = v0;
        if (ok) {
            const float4* p = (const float4*)(x + (((size_t)bImg * Hn + gy) * Hn + gx) * Cn);
            v0 = p[0]; v1 = p[1]; v2 = p[2]; v3 = p[3];
        }
        uint4* row = (uint4*)&xn[tid * 24];
        row[0] = make_uint4(pk2(v0.x,v0.y), pk2(v0.z,v0.w), pk2(v1.x,v1.y), pk2(v1.z,v1.w));
        row[1] = make_uint4(pk2(v2.x,v2.y), pk2(v2.z,v2.w), pk2(v3.x,v3.y), pk2(v3.z,v3.w));
        row[2] = make_uint4(0x00003F80u, 0u, 0u, 0u);   // bf16 1.0 at c16
    }

    const int lane = tid & 63;
    const int wv = tid >> 6;
    const int p16 = lane & 15;
    const int g = lane >> 4;
    const int gh = g >> 1;
    const int sl = wv & 1;        // hidden slice (hid 64*sl ..)
    const int rh = wv >> 1;       // row half (rows rh*4 ..)

    // ---- weight fragments from global (L2-broadcast, 44 KB shared by all) ----
    bf16v8 fw1[4][5];
    #pragma unroll
    for (int u = 0; u < 4; ++u)
        #pragma unroll
        for (int kc = 0; kc < 5; ++kc)
            fw1[u][kc] = *(const bf16v8*)&ws[(16*(4*sl+u) + p16)*160 + kc*32 + g*8];
    bf16v8 fw2[2];
    #pragma unroll
    for (int kc = 0; kc < 2; ++kc)
        fw2[kc] = *(const bf16v8*)&ws[W1E_SH + (sl*16 + p16)*64 + kc*32 + g*8];
    const float4 b2v = *(const float4*)(b2 + 4*g);

    // per-kc LDS site offsets (row-independent): k-slot -> (dy,dx,c0)
    int soff[5];
    #pragma unroll
    for (int kc = 0; kc < 5; ++kc) {
        const int p = (kc < 4) ? (2*kc + gh) : 8;
        const int dy = (0x2A540u >> (2*p)) & 3;
        const int dx = (0x24924u >> (2*p)) & 3;
        const int c0 = (kc == 4 && g >= 2) ? 16 : (g & 1) * 8;  // pad/bias slots
        soff[kc] = (dy * 18 + p16 + dx) * 24 + c0;
    }

    __syncthreads();

    // ---- main: per row, GEMM1 (K=160) -> relu/pack -> GEMM2 partial ----
    #pragma unroll
    for (int ry = 0; ry < 4; ++ry) {
        const int y = rh * 4 + ry;
        bf16v8 bx[5];
        #pragma unroll
        for (int kc = 0; kc < 5; ++kc)
            bx[kc] = *(const bf16v8*)&xn[y * 432 + soff[kc]];

        f32x4 d1[4];
        #pragma unroll
        for (int u = 0; u < 4; ++u) {
            f32x4 acc = {0,0,0,0};
            #pragma unroll
            for (int kc = 0; kc < 5; ++kc)
                acc = __builtin_amdgcn_mfma_f32_16x16x32_bf16(fw1[u][kc], bx[kc], acc, 0,0,0);
            d1[u] = acc;
        }

        // swapped GEMM2: B-frag slot (kc,g,j) == pi(hid) == own d1 registers
        f32x4 acc2 = {0,0,0,0};
        #pragma unroll
        for (int kc = 0; kc < 2; ++kc) {
            unsigned q0 = pk2(fmaxf(d1[2*kc  ][0],0.f), fmaxf(d1[2*kc  ][1],0.f));
            unsigned q1 = pk2(fmaxf(d1[2*kc  ][2],0.f), fmaxf(d1[2*kc  ][3],0.f));
            unsigned q2 = pk2(fmaxf(d1[2*kc+1][0],0.f), fmaxf(d1[2*kc+1][1],0.f));
            unsigned q3 = pk2(fmaxf(d1[2*kc+1][2],0.f), fmaxf(d1[2*kc+1][3],0.f));
            uint4 qq = make_uint4(q0,q1,q2,q3);
            bf16v8 hb = __builtin_bit_cast(bf16v8, qq);
            acc2 = __builtin_amdgcn_mfma_f32_16x16x32_bf16(fw2[kc], hb, acc2, 0,0,0);
        }

        // partial dx: pixel=p16, out=4g..4g+3 (80 B px stride -> 2-way, free)
        float* rp = &red[y][sl][p16][4*g];
        *(float2*)(rp)     = make_float2(acc2[0], acc2[1]);
        *(float2*)(rp + 2) = make_float2(acc2[2], acc2[3]);
    }

    __syncthreads();

    // ---- reduce slices + residual + clip; fully coalesced b128 I/O ----
    #pragma unroll
    for (int e = 0; e < 2; ++e) {
        const int y = 2*wv + e;
        const float* r0 = &red[y][0][p16][4*g];
        const float* r1 = &red[y][1][p16][4*g];
        const int gy = Ybase + y;
        const int gx = Xbase + p16;
        const size_t base = (((size_t)bImg * Hn + gy) * Hn + gx) * Cn + 4*g;
        const float4 xv = *(const float4*)(x + base);
        float4 o;
        o.x = fminf(fmaxf(xv.x + r0[0] + r1[0] + b2v.x, 0.f), 1.f);
        o.y = fminf(fmaxf(xv.y + r0[1] + r1[1] + b2v.y, 0.f), 1.f);
        o.z = fminf(fmaxf(xv.z + r0[2] + r1[2] + b2v.z, 0.f), 1.f);
        o.w = fminf(fmaxf(xv.w + r0[3] + r1[3] + b2v.w, 0.f), 1.f);
        *(float4*)(out + base) = o;
    }
}

extern "C" void kernel_launch(void* const* d_in, const int* in_sizes, int n_in,
                              void* d_out, int out_size, void* d_ws, size_t ws_size,
                              hipStream_t stream) {
    // setup_inputs order: x, perc, W1, b1, W2, b2, lock_release
    const float* x  = (const float*)d_in[0];
    const float* W1 = (const float*)d_in[2];
    const float* b1 = (const float*)d_in[3];
    const float* W2 = (const float*)d_in[4];
    const float* b2 = (const float*)d_in[5];
    float* out = (float*)d_out;
    unsigned short* wsb = (unsigned short*)d_ws;

    hipLaunchKernelGGL(nca_prep, dim3((WS_TOT + 255) / 256), dim3(256), 0, stream,
                       W1, b1, W2, wsb);
    hipLaunchKernelGGL(nca_fwd, dim3(8 * 64 * 32), dim3(256), 0, stream,
                       x, (const unsigned short*)wsb, b2, out);
}